// Round 13
// baseline (609.534 us; speedup 1.0000x reference)
//
#include <hip/hip_runtime.h>
#include <stdint.h>

typedef unsigned short ushort_t;

__device__ __forceinline__ float bf2f(unsigned short u) {
  union { unsigned int i; float f; } c; c.i = ((unsigned int)u) << 16; return c.f;
}
__device__ __forceinline__ unsigned short f2bf(float f) {
  union { float f; unsigned int i; } c; c.f = f;
  unsigned int r = c.i + 0x7FFFu + ((c.i >> 16) & 1u);
  return (unsigned short)(r >> 16);
}
// NaN-propagating relu (tripwire: NaN stays visible)
__device__ __forceinline__ float relu_nanprop(float v) { return (v < 0.f) ? 0.f : v; }

// async global->LDS 16B copy: LDS dest = wave-uniform base + lane*16 (HW-implicit)
__device__ __forceinline__ void async_copy16(const void* g, void* l) {
  __builtin_amdgcn_global_load_lds(
      (const __attribute__((address_space(1))) unsigned int*)(uintptr_t)g,
      (__attribute__((address_space(3))) unsigned int*)(uintptr_t)l,
      16, 0, 0);
}

typedef __attribute__((ext_vector_type(8))) short s16x8;
typedef __attribute__((ext_vector_type(4))) float f32x4;

__device__ __forceinline__ int edge_at(const void* edges, int wide, int idx) {
  if (wide) return (int)((const long long*)edges)[idx];
  return ((const int*)edges)[idx];
}

// ---------------- setup: zero scratch + dtype detects (1 launch) ----------------
__global__ void setup_kernel(int* __restrict__ zreg2, int N,
                             const int* __restrict__ e32, int n32, int* __restrict__ eflag,
                             const unsigned int* __restrict__ x, int nw, int* __restrict__ fF) {
  int b = blockIdx.x, tid = threadIdx.x;
  if (b < 256) {
    int total = 2 * N + 1024;
    for (int i = b * 256 + tid; i < total; i += 256 * 256) zreg2[i] = 0;
  } else if (b == 256) {
    __shared__ int any;
    if (tid == 0) any = 0;
    __syncthreads();
    for (int i = tid; i < 4096; i += 256) {
      int idx = 2 * i + 1;
      if (idx < n32 && e32[idx] != 0) any = 1;
    }
    __syncthreads();
    if (tid == 0) eflag[0] = (any == 0) ? 1 : 0;  // 1 => int64
  } else {
    __shared__ int cnt;
    if (tid == 0) cnt = 0;
    __syncthreads();
    int local = 0;
    for (int i = tid; i < 4096 && i < nw; i += 256) {
      unsigned int low = x[i] & 0xFFFFu;
      unsigned int e = (low >> 7) & 0xFFu;
      if (low != 0u && (e < 96u || e > 144u)) local++;
    }
    atomicAdd(&cnt, local);
    __syncthreads();
    if (tid == 0) fF[0] = (cnt > 1024) ? 1 : 0;  // 1 => float32 inputs
  }
}

// ---------------- cvt_all: x0 cvt + params + 2x weight transpose + hist (1 launch) ----
__global__ void cvt_all_kernel(const void* __restrict__ x0, ushort_t* __restrict__ x0b, int nx,
                               const void* p0, const void* p1, const void* p2,
                               const void* p3, const void* p4, const void* p5,
                               ushort_t* o0, ushort_t* o1, ushort_t* o2,
                               ushort_t* o3, ushort_t* o4, ushort_t* o5,
                               const void* W10, const void* W11, const void* W12, const void* W13,
                               ushort_t* __restrict__ wcat1,
                               const void* W20, const void* W21, const void* W22, const void* W23,
                               ushort_t* __restrict__ wcat2,
                               const void* __restrict__ edges, int* __restrict__ deg,
                               int E, int Nn,
                               const int* __restrict__ eflag, const int* __restrict__ fF) {
  int b = blockIdx.x, tid = threadIdx.x;
  int f = fF[0];
  if (b < 4096) {
    for (int i = b * 256 + tid; i < nx; i += 4096 * 256)
      x0b[i] = f ? f2bf(((const float*)x0)[i]) : ((const ushort_t*)x0)[i];
  } else if (b == 4096) {
    const void* ins[6] = {p0, p1, p2, p3, p4, p5};
    ushort_t* outs[6] = {o0, o1, o2, o3, o4, o5};
    const int segs[7] = {0, 256, 512, 768, 896, 1024, 1152};
    for (int i = tid; i < 1152; i += 256) {
      int s = 0;
      while (i >= segs[s + 1]) s++;
      int li = i - segs[s];
      outs[s][li] = f ? f2bf(((const float*)ins[s])[li]) : ((const ushort_t*)ins[s])[li];
    }
  } else if (b < 4609) {  // layer-1 weights: K=128, C=256 x4 -> wcat1[1024][128]
    const void* Ws[4] = {W10, W11, W12, W13};
    int per = 128 * 256, total = 4 * per;
    for (int i = (b - 4097) * 256 + tid; i < total; i += 512 * 256) {
      int wsel = i / per, rem = i - wsel * per;
      int k = rem >> 8, c = rem & 255;
      ushort_t v = f ? f2bf(((const float*)Ws[wsel])[rem]) : ((const ushort_t*)Ws[wsel])[rem];
      wcat1[(size_t)(wsel * 256 + c) * 128 + k] = v;
    }
  } else if (b < 5121) {  // layer-2 weights: K=256, C=256,256,128,128 -> wcat2[768][256]
    int per01 = 256 * 256, per23 = 256 * 128;
    int total = 2 * per01 + 2 * per23;
    for (int i = (b - 4609) * 256 + tid; i < total; i += 512 * 256) {
      const void* W; int rem, C, rowoff;
      if (i < per01)                 { W = W20; rem = i;                  C = 256; rowoff = 0; }
      else if (i < 2 * per01)        { W = W21; rem = i - per01;          C = 256; rowoff = 256; }
      else if (i < 2 * per01 + per23){ W = W22; rem = i - 2 * per01;      C = 128; rowoff = 512; }
      else                           { W = W23; rem = i - 2 * per01 - per23; C = 128; rowoff = 640; }
      int k = rem / C, c = rem - k * C;
      ushort_t v = f ? f2bf(((const float*)W)[rem]) : ((const ushort_t*)W)[rem];
      wcat2[(size_t)(rowoff + c) * 256 + k] = v;
    }
  } else {  // hist: 1024 blocks
    int wide = eflag[0];
    for (int e = (b - 5121) * 256 + tid; e < E; e += 1024 * 256) {
      int d = edge_at(edges, wide, E + e);
      if (d < 0) d = 0; if (d >= Nn) d = Nn - 1;
      atomicAdd(&deg[d], 1);
    }
  }
}

// ---------------- single-kernel scan: block b redundantly sums deg below its chunk ----
__global__ void scan_kernel(const int* __restrict__ deg, int* __restrict__ offs,
                            int n, int E) {
  int b = blockIdx.x, t = threadIdx.x;
  int base = b * 256;
  int ps = 0;
  for (int i = t; i < base; i += 256) ps += deg[i];
  __shared__ int ws[4];
#pragma unroll
  for (int o = 32; o > 0; o >>= 1) ps += __shfl_down(ps, o);
  if ((t & 63) == 0) ws[t >> 6] = ps;
  __syncthreads();
  int carry = ws[0] + ws[1] + ws[2] + ws[3];
  __shared__ int tmp[256];
  int i = base + t;
  int v = (i < n) ? deg[i] : 0;
  tmp[t] = v;
  __syncthreads();
  for (int off = 1; off < 256; off <<= 1) {
    int x = (t >= off) ? tmp[t - off] : 0;
    __syncthreads();
    tmp[t] += x;
    __syncthreads();
  }
  if (i < n) offs[i] = carry + tmp[t] - v;
  if (b == 0 && t == 0) offs[n] = E;
}

__global__ void scatter_kernel(const void* __restrict__ edges, const int* __restrict__ flag,
                               const int* __restrict__ offs, int* __restrict__ fill,
                               int* __restrict__ srcS, int E, int Nn) {
  int wide = flag[0];
  for (int e = blockIdx.x * blockDim.x + threadIdx.x; e < E; e += gridDim.x * blockDim.x) {
    int s = edge_at(edges, wide, e);
    int d = edge_at(edges, wide, E + e);
    if (d < 0) d = 0; if (d >= Nn) d = Nn - 1;
    if (s < 0) s = 0; if (s >= Nn) s = Nn - 1;
    int p = offs[d] + atomicAdd(&fill[d], 1);
    if (p < 0) p = 0; if (p >= E) p = E - 1;
    srcS[p] = s;
  }
}

// ---------------- fused 4-way GEMM: [q|k|v|h] = A @ Wcat, bf16 in/out ----------------
// R11 config (best measured): 128x128 tile, acc 4x4, global_load_lds staging, grid
// x=M-tile / y=col-tile, hoisted-section SCALAR epilogue (fire-and-forget stores).
// [R12 post-mortem: LDS-coalesced epilogue (+34KB LDS, +barrier) and x=col grid swap
// regressed total by 16us — stores with no dependent consumer were already cheap.]
// [R8: 128x256 tile = 1 wave/SIMD = 10% occ = 204 us. Occupancy >> A-reuse here.]
__global__ __launch_bounds__(256)
void gemm4_kernel(const ushort_t* __restrict__ A, const ushort_t* __restrict__ BT,
                  ushort_t* __restrict__ o0, ushort_t* __restrict__ o1,
                  ushort_t* __restrict__ o2, ushort_t* __restrict__ o3,
                  const ushort_t* __restrict__ bias3,
                  int M, int K, int NC, int b0, int b1, int b2) {
  __shared__ __align__(16) ushort_t As[128 * 32];
  __shared__ __align__(16) ushort_t Bs[128 * 32];
  int tid = threadIdx.x;
  int lane = tid & 63, wave = tid >> 6;
  int tm = blockIdx.x * 128, tn = blockIdx.y * 128;
  int wm = (wave >> 1) * 64, wn = (wave & 1) * 64;
  int q = lane >> 4, l = lane & 15;
  f32x4 acc[4][4];
#pragma unroll
  for (int a = 0; a < 4; a++)
#pragma unroll
    for (int b = 0; b < 4; b++) acc[a][b] = (f32x4){0.f, 0.f, 0.f, 0.f};

  int lrow = lane >> 2, c8 = (lane & 3) * 8;
  for (int k0 = 0; k0 < K; k0 += 32) {
#pragma unroll
    for (int t = 0; t < 2; t++) {
      int chunk = t * 4 + wave;           // 0..7, 16 rows each
      int row = chunk * 16 + lrow;
      int ra = tm + row; if (ra > M - 1) ra = M - 1;
      async_copy16(&A[(size_t)ra * K + k0 + c8], &As[chunk * 512]);
      async_copy16(&BT[(size_t)(tn + row) * K + k0 + c8], &Bs[chunk * 512]);
    }
    __syncthreads();
    s16x8 af[4], bfr[4];
#pragma unroll
    for (int mf = 0; mf < 4; mf++) af[mf] = *(const s16x8*)&As[(wm + mf * 16 + l) * 32 + q * 8];
#pragma unroll
    for (int nf = 0; nf < 4; nf++) bfr[nf] = *(const s16x8*)&Bs[(wn + nf * 16 + l) * 32 + q * 8];
#pragma unroll
    for (int mf = 0; mf < 4; mf++)
#pragma unroll
      for (int nf = 0; nf < 4; nf++)
        acc[mf][nf] = __builtin_amdgcn_mfma_f32_16x16x32_bf16(af[mf], bfr[nf], acc[mf][nf], 0, 0, 0);
    __syncthreads();
  }
  // Hoisted section select (tile is 128-aligned; sections are 128-multiples).
  ushort_t* op; int sbase, w; bool addb = false;
  if (tn < b0)      { op = o0; sbase = 0;  w = b0; }
  else if (tn < b1) { op = o1; sbase = b0; w = b1 - b0; }
  else if (tn < b2) { op = o2; sbase = b1; w = b2 - b1; }
  else              { op = o3; sbase = b2; w = NC - b2; addb = true; }
  int lc0 = tn + wn - sbase + l;
  float bv[4];
#pragma unroll
  for (int nf = 0; nf < 4; nf++) bv[nf] = addb ? bf2f(bias3[lc0 + nf * 16]) : 0.f;
  // C/D layout: col = lane&15, row = (lane>>4)*4 + reg   [m89-verified]
#pragma unroll
  for (int mf = 0; mf < 4; mf++) {
#pragma unroll
    for (int j = 0; j < 4; j++) {
      int r = tm + wm + mf * 16 + q * 4 + j;
      if (r < M) {
#pragma unroll
        for (int nf = 0; nf < 4; nf++)
          op[(size_t)r * w + lc0 + nf * 16] = f2bf(acc[mf][nf][j] + bv[nf]);
      }
    }
  }
}

// ---------------- fused attention + aggregation, one WAVE per dst node ----------------
// Unroll x4 (R7-proven 117us; R9: x8 regresses to 124us — register pressure + tail).
__global__ __launch_bounds__(256)
void attn_kernel(const ushort_t* __restrict__ q, const ushort_t* __restrict__ k,
                 const ushort_t* __restrict__ v, const int* __restrict__ offs,
                 const int* __restrict__ srcS, ushort_t* __restrict__ h, int dout, int Nn) {
  int lane = threadIdx.x & 63, wave = threadIdx.x >> 6;
  int n = blockIdx.x * 4 + wave;
  if (n >= Nn) return;

  ushort4 qq = *(const ushort4*)(q + (size_t)n * 256 + lane * 4);
  float q0 = bf2f(qq.x), q1 = bf2f(qq.y), q2 = bf2f(qq.z), q3 = bf2f(qq.w);

  int e0 = offs[n], e1 = offs[n + 1];
  float a0 = 0.f, a1 = 0.f, a2 = 0.f, a3 = 0.f, wsum = 0.f;
  int j = e0;

  if (dout == 256) {
    for (; j + 4 <= e1; j += 4) {
      int s0 = srcS[j], s1 = srcS[j + 1], s2 = srcS[j + 2], s3 = srcS[j + 3];
      if (s0 < 0 || s0 >= Nn) s0 = 0;
      if (s1 < 0 || s1 >= Nn) s1 = 0;
      if (s2 < 0 || s2 >= Nn) s2 = 0;
      if (s3 < 0 || s3 >= Nn) s3 = 0;
      ushort4 k0 = *(const ushort4*)(k + (size_t)s0 * 256 + lane * 4);
      ushort4 k1 = *(const ushort4*)(k + (size_t)s1 * 256 + lane * 4);
      ushort4 k2 = *(const ushort4*)(k + (size_t)s2 * 256 + lane * 4);
      ushort4 k3 = *(const ushort4*)(k + (size_t)s3 * 256 + lane * 4);
      ushort4 v0 = *(const ushort4*)(v + (size_t)s0 * 256 + lane * 4);
      ushort4 v1 = *(const ushort4*)(v + (size_t)s1 * 256 + lane * 4);
      ushort4 v2 = *(const ushort4*)(v + (size_t)s2 * 256 + lane * 4);
      ushort4 v3 = *(const ushort4*)(v + (size_t)s3 * 256 + lane * 4);
      float p0 = q0 * bf2f(k0.x) + q1 * bf2f(k0.y) + q2 * bf2f(k0.z) + q3 * bf2f(k0.w);
      float p1 = q0 * bf2f(k1.x) + q1 * bf2f(k1.y) + q2 * bf2f(k1.z) + q3 * bf2f(k1.w);
      float p2 = q0 * bf2f(k2.x) + q1 * bf2f(k2.y) + q2 * bf2f(k2.z) + q3 * bf2f(k2.w);
      float p3 = q0 * bf2f(k3.x) + q1 * bf2f(k3.y) + q2 * bf2f(k3.z) + q3 * bf2f(k3.w);
#pragma unroll
      for (int o = 32; o > 0; o >>= 1) {
        p0 += __shfl_xor(p0, o); p1 += __shfl_xor(p1, o);
        p2 += __shfl_xor(p2, o); p3 += __shfl_xor(p3, o);
      }
      float w0 = __expf(p0 * 0.0625f), w1 = __expf(p1 * 0.0625f);
      float w2 = __expf(p2 * 0.0625f), w3 = __expf(p3 * 0.0625f);
      wsum += (w0 + w1) + (w2 + w3);
      a0 += w0 * bf2f(v0.x) + w1 * bf2f(v1.x) + w2 * bf2f(v2.x) + w3 * bf2f(v3.x);
      a1 += w0 * bf2f(v0.y) + w1 * bf2f(v1.y) + w2 * bf2f(v2.y) + w3 * bf2f(v3.y);
      a2 += w0 * bf2f(v0.z) + w1 * bf2f(v1.z) + w2 * bf2f(v2.z) + w3 * bf2f(v3.z);
      a3 += w0 * bf2f(v0.w) + w1 * bf2f(v1.w) + w2 * bf2f(v2.w) + w3 * bf2f(v3.w);
    }
    for (; j < e1; j++) {
      int s = srcS[j];
      if (s < 0 || s >= Nn) s = 0;
      ushort4 kk = *(const ushort4*)(k + (size_t)s * 256 + lane * 4);
      ushort4 vv = *(const ushort4*)(v + (size_t)s * 256 + lane * 4);
      float p = q0 * bf2f(kk.x) + q1 * bf2f(kk.y) + q2 * bf2f(kk.z) + q3 * bf2f(kk.w);
#pragma unroll
      for (int o = 32; o > 0; o >>= 1) p += __shfl_xor(p, o);
      float w = __expf(p * 0.0625f);
      wsum += w;
      a0 += w * bf2f(vv.x); a1 += w * bf2f(vv.y);
      a2 += w * bf2f(vv.z); a3 += w * bf2f(vv.w);
    }
    float inv = 1.f / fmaxf(wsum, 1e-16f);
    size_t idx = (size_t)n * 256 + lane * 4;
    ushort4 hh = *(const ushort4*)(h + idx);
    ushort4 ho;
    ho.x = f2bf(bf2f(hh.x) + a0 * inv);
    ho.y = f2bf(bf2f(hh.y) + a1 * inv);
    ho.z = f2bf(bf2f(hh.z) + a2 * inv);
    ho.w = f2bf(bf2f(hh.w) + a3 * inv);
    *(ushort4*)(h + idx) = ho;
  } else {  // dout == 128: 2 features per lane
    for (; j + 4 <= e1; j += 4) {
      int s0 = srcS[j], s1 = srcS[j + 1], s2 = srcS[j + 2], s3 = srcS[j + 3];
      if (s0 < 0 || s0 >= Nn) s0 = 0;
      if (s1 < 0 || s1 >= Nn) s1 = 0;
      if (s2 < 0 || s2 >= Nn) s2 = 0;
      if (s3 < 0 || s3 >= Nn) s3 = 0;
      ushort4 k0 = *(const ushort4*)(k + (size_t)s0 * 256 + lane * 4);
      ushort4 k1 = *(const ushort4*)(k + (size_t)s1 * 256 + lane * 4);
      ushort4 k2 = *(const ushort4*)(k + (size_t)s2 * 256 + lane * 4);
      ushort4 k3 = *(const ushort4*)(k + (size_t)s3 * 256 + lane * 4);
      ushort2 v0 = *(const ushort2*)(v + (size_t)s0 * 128 + lane * 2);
      ushort2 v1 = *(const ushort2*)(v + (size_t)s1 * 128 + lane * 2);
      ushort2 v2 = *(const ushort2*)(v + (size_t)s2 * 128 + lane * 2);
      ushort2 v3 = *(const ushort2*)(v + (size_t)s3 * 128 + lane * 2);
      float p0 = q0 * bf2f(k0.x) + q1 * bf2f(k0.y) + q2 * bf2f(k0.z) + q3 * bf2f(k0.w);
      float p1 = q0 * bf2f(k1.x) + q1 * bf2f(k1.y) + q2 * bf2f(k1.z) + q3 * bf2f(k1.w);
      float p2 = q0 * bf2f(k2.x) + q1 * bf2f(k2.y) + q2 * bf2f(k2.z) + q3 * bf2f(k2.w);
      float p3 = q0 * bf2f(k3.x) + q1 * bf2f(k3.y) + q2 * bf2f(k3.z) + q3 * bf2f(k3.w);
#pragma unroll
      for (int o = 32; o > 0; o >>= 1) {
        p0 += __shfl_xor(p0, o); p1 += __shfl_xor(p1, o);
        p2 += __shfl_xor(p2, o); p3 += __shfl_xor(p3, o);
      }
      float w0 = __expf(p0 * 0.0625f), w1 = __expf(p1 * 0.0625f);
      float w2 = __expf(p2 * 0.0625f), w3 = __expf(p3 * 0.0625f);
      wsum += (w0 + w1) + (w2 + w3);
      a0 += w0 * bf2f(v0.x) + w1 * bf2f(v1.x) + w2 * bf2f(v2.x) + w3 * bf2f(v3.x);
      a1 += w0 * bf2f(v0.y) + w1 * bf2f(v1.y) + w2 * bf2f(v2.y) + w3 * bf2f(v3.y);
    }
    for (; j < e1; j++) {
      int s = srcS[j];
      if (s < 0 || s >= Nn) s = 0;
      ushort4 kk = *(const ushort4*)(k + (size_t)s * 256 + lane * 4);
      ushort2 vv = *(const ushort2*)(v + (size_t)s * 128 + lane * 2);
      float p = q0 * bf2f(kk.x) + q1 * bf2f(kk.y) + q2 * bf2f(kk.z) + q3 * bf2f(kk.w);
#pragma unroll
      for (int o = 32; o > 0; o >>= 1) p += __shfl_xor(p, o);
      float w = __expf(p * 0.0625f);
      wsum += w;
      a0 += w * bf2f(vv.x); a1 += w * bf2f(vv.y);
    }
    float inv = 1.f / fmaxf(wsum, 1e-16f);
    size_t idx = (size_t)n * 128 + lane * 2;
    ushort2 hh = *(const ushort2*)(h + idx);
    ushort2 ho;
    ho.x = f2bf(bf2f(hh.x) + a0 * inv);
    ho.y = f2bf(bf2f(hh.y) + a1 * inv);
    *(ushort2*)(h + idx) = ho;
  }
}

// ---------------- BatchNorm ----------------
__global__ void bn_stats_kernel(const ushort_t* __restrict__ h, float* __restrict__ sum,
                                float* __restrict__ sumsq, int N, int F) {
  int col = threadIdx.x;
  float s = 0.f, s2 = 0.f;
  for (int r = blockIdx.x; r < N; r += gridDim.x) {
    float x = bf2f(h[(size_t)r * F + col]);
    s += x; s2 += x * x;
  }
  atomicAdd(&sum[col], s);
  atomicAdd(&sumsq[col], s2);
}

// normalize+relu; each block recomputes scale/shift from sums (removes bn_final launch)
__global__ void norm_relu_kernel(const ushort_t* __restrict__ h,
                                 const float* __restrict__ sum, const float* __restrict__ sumsq,
                                 const ushort_t* __restrict__ g, const ushort_t* __restrict__ be,
                                 ushort_t* __restrict__ x1, int N, size_t total, int cmask) {
  __shared__ float sc[256], sh[256];
  int t = threadIdx.x;
  if (t <= cmask) {
    float mu = sum[t] / (float)N;
    float var = sumsq[t] / (float)N - mu * mu;
    float s = bf2f(g[t]) * rsqrtf(var + 1e-5f);
    sc[t] = s;
    sh[t] = bf2f(be[t]) - mu * s;
  }
  __syncthreads();
  for (size_t i = blockIdx.x * (size_t)blockDim.x + t; i < total;
       i += (size_t)gridDim.x * blockDim.x) {
    int c = (int)(i & (size_t)cmask);
    float vv = bf2f(h[i]) * sc[c] + sh[c];
    x1[i] = f2bf(relu_nanprop(vv));
  }
}

// final: BN + residual + relu, dual-dtype out; recomputes scale/shift per block
__global__ void final_kernel(const ushort_t* __restrict__ h,
                             const float* __restrict__ sum, const float* __restrict__ sumsq,
                             const ushort_t* __restrict__ g, const ushort_t* __restrict__ be,
                             const ushort_t* __restrict__ x0b, void* __restrict__ out,
                             const int* __restrict__ flagF, int N, size_t total) {
  __shared__ float sc[128], sh[128];
  int t = threadIdx.x;
  if (t < 128) {
    float mu = sum[t] / (float)N;
    float var = sumsq[t] / (float)N - mu * mu;
    float s = bf2f(g[t]) * rsqrtf(var + 1e-5f);
    sc[t] = s;
    sh[t] = bf2f(be[t]) - mu * s;
  }
  __syncthreads();
  int f = flagF[0];
  for (size_t i = blockIdx.x * (size_t)blockDim.x + t; i < total;
       i += (size_t)gridDim.x * blockDim.x) {
    int c = (int)(i & 127);
    float vv = bf2f(h[i]) * sc[c] + sh[c] + bf2f(x0b[i]);
    vv = relu_nanprop(vv);
    if (f) ((float*)out)[i] = vv;
    else   ((ushort_t*)out)[i] = f2bf(vv);
  }
}

extern "C" void kernel_launch(void* const* d_in, const int* in_sizes, int n_in,
                              void* d_out, int out_size, void* d_ws, size_t ws_size,
                              hipStream_t stream) {
  const void* x0  = d_in[0];
  const void* edges = d_in[1];
  const void* Wq1 = d_in[2];
  const void* Wk1 = d_in[3];
  const void* Wv1 = d_in[4];
  const void* Wr1 = d_in[5];
  const void* b1  = d_in[6];
  const void* gw1 = d_in[7];
  const void* bw1 = d_in[8];
  const void* Wq2 = d_in[9];
  const void* Wk2 = d_in[10];
  const void* Wv2 = d_in[11];
  const void* Wr2 = d_in[12];
  const void* b2  = d_in[13];
  const void* gw2 = d_in[14];
  const void* bw2 = d_in[15];

  int N = in_sizes[0] / 128;
  int E = in_sizes[1] / 2;
  int NCHUNK = (N + 255) / 256;
  int MT = (N + 127) / 128;

  uintptr_t base = (uintptr_t)d_ws;
  auto carve = [&](size_t bytes) -> void* {
    uintptr_t p = base;
    base += (bytes + 255) & ~(size_t)255;
    return (void*)p;
  };
  ushort_t* x0b = (ushort_t*)carve((size_t)N * 128 * 2);
  ushort_t* qb = (ushort_t*)carve((size_t)N * 256 * 2);
  ushort_t* kb = (ushort_t*)carve((size_t)N * 256 * 2);
  ushort_t* vb = (ushort_t*)carve((size_t)N * 256 * 2);
  ushort_t* hb = (ushort_t*)carve((size_t)N * 256 * 2);
  ushort_t* x1 = (ushort_t*)carve((size_t)N * 256 * 2);
  ushort_t* wcat1 = (ushort_t*)carve((size_t)1024 * 128 * 2);
  ushort_t* wcat2 = (ushort_t*)carve((size_t)768 * 256 * 2);
  ushort_t* b1b  = (ushort_t*)carve(256 * 2);
  ushort_t* g1b  = (ushort_t*)carve(256 * 2);
  ushort_t* be1b = (ushort_t*)carve(256 * 2);
  ushort_t* b2b  = (ushort_t*)carve(128 * 2);
  ushort_t* g2b  = (ushort_t*)carve(128 * 2);
  ushort_t* be2b = (ushort_t*)carve(128 * 2);
  int* offs = (int*)carve((size_t)(N + 1) * 4);
  int* srcS = (int*)carve((size_t)E * 4);
  // zeroed region: deg(N) fill(N) sums(1024 floats)
  int nzero = 2 * N + 1024;
  int* zreg2 = (int*)carve((size_t)nzero * 4);
  int* deg   = zreg2;
  int* fill  = zreg2 + N;
  float* sum1 = (float*)(zreg2 + 2 * N);
  float* sq1  = sum1 + 256;
  float* sum2 = sum1 + 512;
  float* sq2  = sum1 + 640;
  int* eflag = (int*)carve(256);   // [0]=edge wide, [1]=float32 flag (setup writes)
  int* fF = eflag + 1;

  size_t needed = base - (uintptr_t)d_ws;
  if (needed > ws_size) return;

  // 1: zero + dtype detects
  setup_kernel<<<258, 256, 0, stream>>>(zreg2, N, (const int*)edges, 2 * E, eflag,
                                        (const unsigned int*)x0, N * 128, fF);
  // 2: x0 cvt + params + weight transposes + hist
  cvt_all_kernel<<<6145, 256, 0, stream>>>(x0, x0b, N * 128,
                                           b1, gw1, bw1, b2, gw2, bw2,
                                           b1b, g1b, be1b, b2b, g2b, be2b,
                                           Wq1, Wk1, Wv1, Wr1, wcat1,
                                           Wq2, Wk2, Wv2, Wr2, wcat2,
                                           edges, deg, E, N, eflag, fF);
  // 3-4: scan + scatter
  scan_kernel<<<NCHUNK, 256, 0, stream>>>(deg, offs, N, E);
  scatter_kernel<<<1024, 256, 0, stream>>>(edges, eflag, offs, fill, srcS, E, N);

  dim3 gA1(MT, 8);   // x = M tile, y = col tile (R11 best)
  dim3 gA2(MT, 6);
  int gAttn = (N + 3) / 4;        // one wave per node
  // Layer 1
  gemm4_kernel<<<gA1, 256, 0, stream>>>(x0b, wcat1, qb, kb, vb, hb, b1b,
                                        N, 128, 1024, 256, 512, 768);
  attn_kernel<<<gAttn, 256, 0, stream>>>(qb, kb, vb, offs, srcS, hb, 256, N);
  bn_stats_kernel<<<512, 256, 0, stream>>>(hb, sum1, sq1, N, 256);
  norm_relu_kernel<<<4096, 256, 0, stream>>>(hb, sum1, sq1, g1b, be1b, x1, N,
                                             (size_t)N * 256, 255);
  // Layer 2
  gemm4_kernel<<<gA2, 256, 0, stream>>>(x1, wcat2, qb, kb, vb, hb, b2b,
                                        N, 256, 768, 256, 512, 640);
  attn_kernel<<<gAttn, 256, 0, stream>>>(qb, kb, vb, offs, srcS, hb, 128, N);
  bn_stats_kernel<<<512, 128, 0, stream>>>(hb, sum2, sq2, N, 128);
  final_kernel<<<4096, 256, 0, stream>>>(hb, sum2, sq2, g2b, be2b, x0b, d_out, fF, N,
                                         (size_t)N * 128);
}

// Round 14
// 581.027 us; speedup vs baseline: 1.0491x; 1.0491x over previous
//
#include <hip/hip_runtime.h>
#include <stdint.h>

typedef unsigned short ushort_t;

__device__ __forceinline__ float bf2f(unsigned short u) {
  union { unsigned int i; float f; } c; c.i = ((unsigned int)u) << 16; return c.f;
}
__device__ __forceinline__ unsigned short f2bf(float f) {
  union { float f; unsigned int i; } c; c.f = f;
  unsigned int r = c.i + 0x7FFFu + ((c.i >> 16) & 1u);
  return (unsigned short)(r >> 16);
}
// NaN-propagating relu (tripwire: NaN stays visible)
__device__ __forceinline__ float relu_nanprop(float v) { return (v < 0.f) ? 0.f : v; }

// async global->LDS 16B copy: LDS dest = wave-uniform base + lane*16 (HW-implicit)
__device__ __forceinline__ void async_copy16(const void* g, void* l) {
  __builtin_amdgcn_global_load_lds(
      (const __attribute__((address_space(1))) unsigned int*)(uintptr_t)g,
      (__attribute__((address_space(3))) unsigned int*)(uintptr_t)l,
      16, 0, 0);
}

typedef __attribute__((ext_vector_type(8))) short s16x8;
typedef __attribute__((ext_vector_type(4))) float f32x4;

__device__ __forceinline__ int edge_at(const void* edges, int wide, int idx) {
  if (wide) return (int)((const long long*)edges)[idx];
  return ((const int*)edges)[idx];
}

// ---------------- setup: zero scratch + dtype detects (1 launch) ----------------
__global__ void setup_kernel(int* __restrict__ zreg2, int N,
                             const int* __restrict__ e32, int n32, int* __restrict__ eflag,
                             const unsigned int* __restrict__ x, int nw, int* __restrict__ fF) {
  int b = blockIdx.x, tid = threadIdx.x;
  if (b < 256) {
    int total = 2 * N + 1024;
    for (int i = b * 256 + tid; i < total; i += 256 * 256) zreg2[i] = 0;
  } else if (b == 256) {
    __shared__ int any;
    if (tid == 0) any = 0;
    __syncthreads();
    for (int i = tid; i < 4096; i += 256) {
      int idx = 2 * i + 1;
      if (idx < n32 && e32[idx] != 0) any = 1;
    }
    __syncthreads();
    if (tid == 0) eflag[0] = (any == 0) ? 1 : 0;  // 1 => int64
  } else {
    __shared__ int cnt;
    if (tid == 0) cnt = 0;
    __syncthreads();
    int local = 0;
    for (int i = tid; i < 4096 && i < nw; i += 256) {
      unsigned int low = x[i] & 0xFFFFu;
      unsigned int e = (low >> 7) & 0xFFu;
      if (low != 0u && (e < 96u || e > 144u)) local++;
    }
    atomicAdd(&cnt, local);
    __syncthreads();
    if (tid == 0) fF[0] = (cnt > 1024) ? 1 : 0;  // 1 => float32 inputs
  }
}

// ---------------- cvt_all: x0 cvt + params + 2x weight transpose + hist (1 launch) ----
__global__ void cvt_all_kernel(const void* __restrict__ x0, ushort_t* __restrict__ x0b, int nx,
                               const void* p0, const void* p1, const void* p2,
                               const void* p3, const void* p4, const void* p5,
                               ushort_t* o0, ushort_t* o1, ushort_t* o2,
                               ushort_t* o3, ushort_t* o4, ushort_t* o5,
                               const void* W10, const void* W11, const void* W12, const void* W13,
                               ushort_t* __restrict__ wcat1,
                               const void* W20, const void* W21, const void* W22, const void* W23,
                               ushort_t* __restrict__ wcat2,
                               const void* __restrict__ edges, int* __restrict__ deg,
                               int E, int Nn,
                               const int* __restrict__ eflag, const int* __restrict__ fF) {
  int b = blockIdx.x, tid = threadIdx.x;
  int f = fF[0];
  if (b < 4096) {
    for (int i = b * 256 + tid; i < nx; i += 4096 * 256)
      x0b[i] = f ? f2bf(((const float*)x0)[i]) : ((const ushort_t*)x0)[i];
  } else if (b == 4096) {
    const void* ins[6] = {p0, p1, p2, p3, p4, p5};
    ushort_t* outs[6] = {o0, o1, o2, o3, o4, o5};
    const int segs[7] = {0, 256, 512, 768, 896, 1024, 1152};
    for (int i = tid; i < 1152; i += 256) {
      int s = 0;
      while (i >= segs[s + 1]) s++;
      int li = i - segs[s];
      outs[s][li] = f ? f2bf(((const float*)ins[s])[li]) : ((const ushort_t*)ins[s])[li];
    }
  } else if (b < 4609) {  // layer-1 weights: K=128, C=256 x4 -> wcat1[1024][128]
    const void* Ws[4] = {W10, W11, W12, W13};
    int per = 128 * 256, total = 4 * per;
    for (int i = (b - 4097) * 256 + tid; i < total; i += 512 * 256) {
      int wsel = i / per, rem = i - wsel * per;
      int k = rem >> 8, c = rem & 255;
      ushort_t v = f ? f2bf(((const float*)Ws[wsel])[rem]) : ((const ushort_t*)Ws[wsel])[rem];
      wcat1[(size_t)(wsel * 256 + c) * 128 + k] = v;
    }
  } else if (b < 5121) {  // layer-2 weights: K=256, C=256,256,128,128 -> wcat2[768][256]
    int per01 = 256 * 256, per23 = 256 * 128;
    int total = 2 * per01 + 2 * per23;
    for (int i = (b - 4609) * 256 + tid; i < total; i += 512 * 256) {
      const void* W; int rem, C, rowoff;
      if (i < per01)                 { W = W20; rem = i;                  C = 256; rowoff = 0; }
      else if (i < 2 * per01)        { W = W21; rem = i - per01;          C = 256; rowoff = 256; }
      else if (i < 2 * per01 + per23){ W = W22; rem = i - 2 * per01;      C = 128; rowoff = 512; }
      else                           { W = W23; rem = i - 2 * per01 - per23; C = 128; rowoff = 640; }
      int k = rem / C, c = rem - k * C;
      ushort_t v = f ? f2bf(((const float*)W)[rem]) : ((const ushort_t*)W)[rem];
      wcat2[(size_t)(rowoff + c) * 256 + k] = v;
    }
  } else {  // hist: 1024 blocks
    int wide = eflag[0];
    for (int e = (b - 5121) * 256 + tid; e < E; e += 1024 * 256) {
      int d = edge_at(edges, wide, E + e);
      if (d < 0) d = 0; if (d >= Nn) d = Nn - 1;
      atomicAdd(&deg[d], 1);
    }
  }
}

// 3-phase parallel scan (chunk = 256): supports N <= 65536
// [R13 post-mortem: single-kernel scan with per-block redundant prefix is a serial
// dependent-load chain (~195 iters in the last block) => ~+20us. Keep 3-phase.]
__global__ void chunk_sum_kernel(const int* __restrict__ deg, int* __restrict__ csum, int n) {
  int b = blockIdx.x, t = threadIdx.x, i = b * 256 + t;
  int v = (i < n) ? deg[i] : 0;
  __shared__ int ws[4];
#pragma unroll
  for (int o = 32; o > 0; o >>= 1) v += __shfl_down(v, o);
  if ((t & 63) == 0) ws[t >> 6] = v;
  __syncthreads();
  if (t == 0) csum[b] = ws[0] + ws[1] + ws[2] + ws[3];
}

__global__ void scan_small_kernel(const int* __restrict__ csum, int* __restrict__ cpre,
                                  int nc, int* __restrict__ offs, int N) {
  __shared__ int tmp[256];
  int t = threadIdx.x;
  int v = (t < nc) ? csum[t] : 0;
  tmp[t] = v;
  __syncthreads();
  for (int off = 1; off < 256; off <<= 1) {
    int x = (t >= off) ? tmp[t - off] : 0;
    __syncthreads();
    tmp[t] += x;
    __syncthreads();
  }
  if (t < nc) cpre[t] = tmp[t] - v;
  if (t == 255) offs[N] = tmp[255];
}

__global__ void scan_final_kernel(const int* __restrict__ deg, const int* __restrict__ cpre,
                                  int* __restrict__ offs, int n) {
  int b = blockIdx.x, t = threadIdx.x, i = b * 256 + t;
  __shared__ int tmp[256];
  int v = (i < n) ? deg[i] : 0;
  tmp[t] = v;
  __syncthreads();
  for (int off = 1; off < 256; off <<= 1) {
    int x = (t >= off) ? tmp[t - off] : 0;
    __syncthreads();
    tmp[t] += x;
    __syncthreads();
  }
  if (i < n) offs[i] = cpre[b] + tmp[t] - v;
}

__global__ void scatter_kernel(const void* __restrict__ edges, const int* __restrict__ flag,
                               const int* __restrict__ offs, int* __restrict__ fill,
                               int* __restrict__ srcS, int E, int Nn) {
  int wide = flag[0];
  for (int e = blockIdx.x * blockDim.x + threadIdx.x; e < E; e += gridDim.x * blockDim.x) {
    int s = edge_at(edges, wide, e);
    int d = edge_at(edges, wide, E + e);
    if (d < 0) d = 0; if (d >= Nn) d = Nn - 1;
    if (s < 0) s = 0; if (s >= Nn) s = Nn - 1;
    int p = offs[d] + atomicAdd(&fill[d], 1);
    if (p < 0) p = 0; if (p >= E) p = E - 1;
    srcS[p] = s;
  }
}

// ---------------- fused 4-way GEMM: [q|k|v|h] = A @ Wcat, bf16 in/out ----------------
// R11 config (best measured): 128x128 tile, acc 4x4, global_load_lds staging, grid
// x=M-tile / y=col-tile, hoisted-section SCALAR epilogue (fire-and-forget stores).
// [R12: LDS-coalesced epilogue (+34KB LDS, +barrier) and x=col grid swap regressed;
//  stores with no dependent consumer were already cheap.]
// [R8: 128x256 tile = 1 wave/SIMD = 10% occ = 204 us. Occupancy >> A-reuse here.]
__global__ __launch_bounds__(256)
void gemm4_kernel(const ushort_t* __restrict__ A, const ushort_t* __restrict__ BT,
                  ushort_t* __restrict__ o0, ushort_t* __restrict__ o1,
                  ushort_t* __restrict__ o2, ushort_t* __restrict__ o3,
                  const ushort_t* __restrict__ bias3,
                  int M, int K, int NC, int b0, int b1, int b2) {
  __shared__ __align__(16) ushort_t As[128 * 32];
  __shared__ __align__(16) ushort_t Bs[128 * 32];
  int tid = threadIdx.x;
  int lane = tid & 63, wave = tid >> 6;
  int tm = blockIdx.x * 128, tn = blockIdx.y * 128;
  int wm = (wave >> 1) * 64, wn = (wave & 1) * 64;
  int q = lane >> 4, l = lane & 15;
  f32x4 acc[4][4];
#pragma unroll
  for (int a = 0; a < 4; a++)
#pragma unroll
    for (int b = 0; b < 4; b++) acc[a][b] = (f32x4){0.f, 0.f, 0.f, 0.f};

  int lrow = lane >> 2, c8 = (lane & 3) * 8;
  for (int k0 = 0; k0 < K; k0 += 32) {
#pragma unroll
    for (int t = 0; t < 2; t++) {
      int chunk = t * 4 + wave;           // 0..7, 16 rows each
      int row = chunk * 16 + lrow;
      int ra = tm + row; if (ra > M - 1) ra = M - 1;
      async_copy16(&A[(size_t)ra * K + k0 + c8], &As[chunk * 512]);
      async_copy16(&BT[(size_t)(tn + row) * K + k0 + c8], &Bs[chunk * 512]);
    }
    __syncthreads();
    s16x8 af[4], bfr[4];
#pragma unroll
    for (int mf = 0; mf < 4; mf++) af[mf] = *(const s16x8*)&As[(wm + mf * 16 + l) * 32 + q * 8];
#pragma unroll
    for (int nf = 0; nf < 4; nf++) bfr[nf] = *(const s16x8*)&Bs[(wn + nf * 16 + l) * 32 + q * 8];
#pragma unroll
    for (int mf = 0; mf < 4; mf++)
#pragma unroll
      for (int nf = 0; nf < 4; nf++)
        acc[mf][nf] = __builtin_amdgcn_mfma_f32_16x16x32_bf16(af[mf], bfr[nf], acc[mf][nf], 0, 0, 0);
    __syncthreads();
  }
  // Hoisted section select (tile is 128-aligned; sections are 128-multiples).
  ushort_t* op; int sbase, w; bool addb = false;
  if (tn < b0)      { op = o0; sbase = 0;  w = b0; }
  else if (tn < b1) { op = o1; sbase = b0; w = b1 - b0; }
  else if (tn < b2) { op = o2; sbase = b1; w = b2 - b1; }
  else              { op = o3; sbase = b2; w = NC - b2; addb = true; }
  int lc0 = tn + wn - sbase + l;
  float bv[4];
#pragma unroll
  for (int nf = 0; nf < 4; nf++) bv[nf] = addb ? bf2f(bias3[lc0 + nf * 16]) : 0.f;
  // C/D layout: col = lane&15, row = (lane>>4)*4 + reg   [m89-verified]
#pragma unroll
  for (int mf = 0; mf < 4; mf++) {
#pragma unroll
    for (int j = 0; j < 4; j++) {
      int r = tm + wm + mf * 16 + q * 4 + j;
      if (r < M) {
#pragma unroll
        for (int nf = 0; nf < 4; nf++)
          op[(size_t)r * w + lc0 + nf * 16] = f2bf(acc[mf][nf][j] + bv[nf]);
      }
    }
  }
}

// ---------------- fused attention + aggregation, one WAVE per dst node ----------------
// Unroll x4 (R7-proven 117us; R9: x8 regresses to 124us — register pressure + tail).
__global__ __launch_bounds__(256)
void attn_kernel(const ushort_t* __restrict__ q, const ushort_t* __restrict__ k,
                 const ushort_t* __restrict__ v, const int* __restrict__ offs,
                 const int* __restrict__ srcS, ushort_t* __restrict__ h, int dout, int Nn) {
  int lane = threadIdx.x & 63, wave = threadIdx.x >> 6;
  int n = blockIdx.x * 4 + wave;
  if (n >= Nn) return;

  ushort4 qq = *(const ushort4*)(q + (size_t)n * 256 + lane * 4);
  float q0 = bf2f(qq.x), q1 = bf2f(qq.y), q2 = bf2f(qq.z), q3 = bf2f(qq.w);

  int e0 = offs[n], e1 = offs[n + 1];
  float a0 = 0.f, a1 = 0.f, a2 = 0.f, a3 = 0.f, wsum = 0.f;
  int j = e0;

  if (dout == 256) {
    for (; j + 4 <= e1; j += 4) {
      int s0 = srcS[j], s1 = srcS[j + 1], s2 = srcS[j + 2], s3 = srcS[j + 3];
      if (s0 < 0 || s0 >= Nn) s0 = 0;
      if (s1 < 0 || s1 >= Nn) s1 = 0;
      if (s2 < 0 || s2 >= Nn) s2 = 0;
      if (s3 < 0 || s3 >= Nn) s3 = 0;
      ushort4 k0 = *(const ushort4*)(k + (size_t)s0 * 256 + lane * 4);
      ushort4 k1 = *(const ushort4*)(k + (size_t)s1 * 256 + lane * 4);
      ushort4 k2 = *(const ushort4*)(k + (size_t)s2 * 256 + lane * 4);
      ushort4 k3 = *(const ushort4*)(k + (size_t)s3 * 256 + lane * 4);
      ushort4 v0 = *(const ushort4*)(v + (size_t)s0 * 256 + lane * 4);
      ushort4 v1 = *(const ushort4*)(v + (size_t)s1 * 256 + lane * 4);
      ushort4 v2 = *(const ushort4*)(v + (size_t)s2 * 256 + lane * 4);
      ushort4 v3 = *(const ushort4*)(v + (size_t)s3 * 256 + lane * 4);
      float p0 = q0 * bf2f(k0.x) + q1 * bf2f(k0.y) + q2 * bf2f(k0.z) + q3 * bf2f(k0.w);
      float p1 = q0 * bf2f(k1.x) + q1 * bf2f(k1.y) + q2 * bf2f(k1.z) + q3 * bf2f(k1.w);
      float p2 = q0 * bf2f(k2.x) + q1 * bf2f(k2.y) + q2 * bf2f(k2.z) + q3 * bf2f(k2.w);
      float p3 = q0 * bf2f(k3.x) + q1 * bf2f(k3.y) + q2 * bf2f(k3.z) + q3 * bf2f(k3.w);
#pragma unroll
      for (int o = 32; o > 0; o >>= 1) {
        p0 += __shfl_xor(p0, o); p1 += __shfl_xor(p1, o);
        p2 += __shfl_xor(p2, o); p3 += __shfl_xor(p3, o);
      }
      float w0 = __expf(p0 * 0.0625f), w1 = __expf(p1 * 0.0625f);
      float w2 = __expf(p2 * 0.0625f), w3 = __expf(p3 * 0.0625f);
      wsum += (w0 + w1) + (w2 + w3);
      a0 += w0 * bf2f(v0.x) + w1 * bf2f(v1.x) + w2 * bf2f(v2.x) + w3 * bf2f(v3.x);
      a1 += w0 * bf2f(v0.y) + w1 * bf2f(v1.y) + w2 * bf2f(v2.y) + w3 * bf2f(v3.y);
      a2 += w0 * bf2f(v0.z) + w1 * bf2f(v1.z) + w2 * bf2f(v2.z) + w3 * bf2f(v3.z);
      a3 += w0 * bf2f(v0.w) + w1 * bf2f(v1.w) + w2 * bf2f(v2.w) + w3 * bf2f(v3.w);
    }
    for (; j < e1; j++) {
      int s = srcS[j];
      if (s < 0 || s >= Nn) s = 0;
      ushort4 kk = *(const ushort4*)(k + (size_t)s * 256 + lane * 4);
      ushort4 vv = *(const ushort4*)(v + (size_t)s * 256 + lane * 4);
      float p = q0 * bf2f(kk.x) + q1 * bf2f(kk.y) + q2 * bf2f(kk.z) + q3 * bf2f(kk.w);
#pragma unroll
      for (int o = 32; o > 0; o >>= 1) p += __shfl_xor(p, o);
      float w = __expf(p * 0.0625f);
      wsum += w;
      a0 += w * bf2f(vv.x); a1 += w * bf2f(vv.y);
      a2 += w * bf2f(vv.z); a3 += w * bf2f(vv.w);
    }
    float inv = 1.f / fmaxf(wsum, 1e-16f);
    size_t idx = (size_t)n * 256 + lane * 4;
    ushort4 hh = *(const ushort4*)(h + idx);
    ushort4 ho;
    ho.x = f2bf(bf2f(hh.x) + a0 * inv);
    ho.y = f2bf(bf2f(hh.y) + a1 * inv);
    ho.z = f2bf(bf2f(hh.z) + a2 * inv);
    ho.w = f2bf(bf2f(hh.w) + a3 * inv);
    *(ushort4*)(h + idx) = ho;
  } else {  // dout == 128: 2 features per lane
    for (; j + 4 <= e1; j += 4) {
      int s0 = srcS[j], s1 = srcS[j + 1], s2 = srcS[j + 2], s3 = srcS[j + 3];
      if (s0 < 0 || s0 >= Nn) s0 = 0;
      if (s1 < 0 || s1 >= Nn) s1 = 0;
      if (s2 < 0 || s2 >= Nn) s2 = 0;
      if (s3 < 0 || s3 >= Nn) s3 = 0;
      ushort4 k0 = *(const ushort4*)(k + (size_t)s0 * 256 + lane * 4);
      ushort4 k1 = *(const ushort4*)(k + (size_t)s1 * 256 + lane * 4);
      ushort4 k2 = *(const ushort4*)(k + (size_t)s2 * 256 + lane * 4);
      ushort4 k3 = *(const ushort4*)(k + (size_t)s3 * 256 + lane * 4);
      ushort2 v0 = *(const ushort2*)(v + (size_t)s0 * 128 + lane * 2);
      ushort2 v1 = *(const ushort2*)(v + (size_t)s1 * 128 + lane * 2);
      ushort2 v2 = *(const ushort2*)(v + (size_t)s2 * 128 + lane * 2);
      ushort2 v3 = *(const ushort2*)(v + (size_t)s3 * 128 + lane * 2);
      float p0 = q0 * bf2f(k0.x) + q1 * bf2f(k0.y) + q2 * bf2f(k0.z) + q3 * bf2f(k0.w);
      float p1 = q0 * bf2f(k1.x) + q1 * bf2f(k1.y) + q2 * bf2f(k1.z) + q3 * bf2f(k1.w);
      float p2 = q0 * bf2f(k2.x) + q1 * bf2f(k2.y) + q2 * bf2f(k2.z) + q3 * bf2f(k2.w);
      float p3 = q0 * bf2f(k3.x) + q1 * bf2f(k3.y) + q2 * bf2f(k3.z) + q3 * bf2f(k3.w);
#pragma unroll
      for (int o = 32; o > 0; o >>= 1) {
        p0 += __shfl_xor(p0, o); p1 += __shfl_xor(p1, o);
        p2 += __shfl_xor(p2, o); p3 += __shfl_xor(p3, o);
      }
      float w0 = __expf(p0 * 0.0625f), w1 = __expf(p1 * 0.0625f);
      float w2 = __expf(p2 * 0.0625f), w3 = __expf(p3 * 0.0625f);
      wsum += (w0 + w1) + (w2 + w3);
      a0 += w0 * bf2f(v0.x) + w1 * bf2f(v1.x) + w2 * bf2f(v2.x) + w3 * bf2f(v3.x);
      a1 += w0 * bf2f(v0.y) + w1 * bf2f(v1.y) + w2 * bf2f(v2.y) + w3 * bf2f(v3.y);
    }
    for (; j < e1; j++) {
      int s = srcS[j];
      if (s < 0 || s >= Nn) s = 0;
      ushort4 kk = *(const ushort4*)(k + (size_t)s * 256 + lane * 4);
      ushort2 vv = *(const ushort2*)(v + (size_t)s * 128 + lane * 2);
      float p = q0 * bf2f(kk.x) + q1 * bf2f(kk.y) + q2 * bf2f(kk.z) + q3 * bf2f(kk.w);
#pragma unroll
      for (int o = 32; o > 0; o >>= 1) p += __shfl_xor(p, o);
      float w = __expf(p * 0.0625f);
      wsum += w;
      a0 += w * bf2f(vv.x); a1 += w * bf2f(vv.y);
    }
    float inv = 1.f / fmaxf(wsum, 1e-16f);
    size_t idx = (size_t)n * 128 + lane * 2;
    ushort2 hh = *(const ushort2*)(h + idx);
    ushort2 ho;
    ho.x = f2bf(bf2f(hh.x) + a0 * inv);
    ho.y = f2bf(bf2f(hh.y) + a1 * inv);
    *(ushort2*)(h + idx) = ho;
  }
}

// ---------------- BatchNorm ----------------
__global__ void bn_stats_kernel(const ushort_t* __restrict__ h, float* __restrict__ sum,
                                float* __restrict__ sumsq, int N, int F) {
  int col = threadIdx.x;
  float s = 0.f, s2 = 0.f;
  for (int r = blockIdx.x; r < N; r += gridDim.x) {
    float x = bf2f(h[(size_t)r * F + col]);
    s += x; s2 += x * x;
  }
  atomicAdd(&sum[col], s);
  atomicAdd(&sumsq[col], s2);
}

// normalize+relu; each block recomputes scale/shift from sums (removes bn_final launch)
__global__ void norm_relu_kernel(const ushort_t* __restrict__ h,
                                 const float* __restrict__ sum, const float* __restrict__ sumsq,
                                 const ushort_t* __restrict__ g, const ushort_t* __restrict__ be,
                                 ushort_t* __restrict__ x1, int N, size_t total, int cmask) {
  __shared__ float sc[256], sh[256];
  int t = threadIdx.x;
  if (t <= cmask) {
    float mu = sum[t] / (float)N;
    float var = sumsq[t] / (float)N - mu * mu;
    float s = bf2f(g[t]) * rsqrtf(var + 1e-5f);
    sc[t] = s;
    sh[t] = bf2f(be[t]) - mu * s;
  }
  __syncthreads();
  for (size_t i = blockIdx.x * (size_t)blockDim.x + t; i < total;
       i += (size_t)gridDim.x * blockDim.x) {
    int c = (int)(i & (size_t)cmask);
    float vv = bf2f(h[i]) * sc[c] + sh[c];
    x1[i] = f2bf(relu_nanprop(vv));
  }
}

// final: BN + residual + relu, dual-dtype out; recomputes scale/shift per block
__global__ void final_kernel(const ushort_t* __restrict__ h,
                             const float* __restrict__ sum, const float* __restrict__ sumsq,
                             const ushort_t* __restrict__ g, const ushort_t* __restrict__ be,
                             const ushort_t* __restrict__ x0b, void* __restrict__ out,
                             const int* __restrict__ flagF, int N, size_t total) {
  __shared__ float sc[128], sh[128];
  int t = threadIdx.x;
  if (t < 128) {
    float mu = sum[t] / (float)N;
    float var = sumsq[t] / (float)N - mu * mu;
    float s = bf2f(g[t]) * rsqrtf(var + 1e-5f);
    sc[t] = s;
    sh[t] = bf2f(be[t]) - mu * s;
  }
  __syncthreads();
  int f = flagF[0];
  for (size_t i = blockIdx.x * (size_t)blockDim.x + t; i < total;
       i += (size_t)gridDim.x * blockDim.x) {
    int c = (int)(i & 127);
    float vv = bf2f(h[i]) * sc[c] + sh[c] + bf2f(x0b[i]);
    vv = relu_nanprop(vv);
    if (f) ((float*)out)[i] = vv;
    else   ((ushort_t*)out)[i] = f2bf(vv);
  }
}

extern "C" void kernel_launch(void* const* d_in, const int* in_sizes, int n_in,
                              void* d_out, int out_size, void* d_ws, size_t ws_size,
                              hipStream_t stream) {
  const void* x0  = d_in[0];
  const void* edges = d_in[1];
  const void* Wq1 = d_in[2];
  const void* Wk1 = d_in[3];
  const void* Wv1 = d_in[4];
  const void* Wr1 = d_in[5];
  const void* b1  = d_in[6];
  const void* gw1 = d_in[7];
  const void* bw1 = d_in[8];
  const void* Wq2 = d_in[9];
  const void* Wk2 = d_in[10];
  const void* Wv2 = d_in[11];
  const void* Wr2 = d_in[12];
  const void* b2  = d_in[13];
  const void* gw2 = d_in[14];
  const void* bw2 = d_in[15];

  int N = in_sizes[0] / 128;
  int E = in_sizes[1] / 2;
  int NCHUNK = (N + 255) / 256;
  int MT = (N + 127) / 128;

  uintptr_t base = (uintptr_t)d_ws;
  auto carve = [&](size_t bytes) -> void* {
    uintptr_t p = base;
    base += (bytes + 255) & ~(size_t)255;
    return (void*)p;
  };
  ushort_t* x0b = (ushort_t*)carve((size_t)N * 128 * 2);
  ushort_t* qb = (ushort_t*)carve((size_t)N * 256 * 2);
  ushort_t* kb = (ushort_t*)carve((size_t)N * 256 * 2);
  ushort_t* vb = (ushort_t*)carve((size_t)N * 256 * 2);
  ushort_t* hb = (ushort_t*)carve((size_t)N * 256 * 2);
  ushort_t* x1 = (ushort_t*)carve((size_t)N * 256 * 2);
  ushort_t* wcat1 = (ushort_t*)carve((size_t)1024 * 128 * 2);
  ushort_t* wcat2 = (ushort_t*)carve((size_t)768 * 256 * 2);
  ushort_t* b1b  = (ushort_t*)carve(256 * 2);
  ushort_t* g1b  = (ushort_t*)carve(256 * 2);
  ushort_t* be1b = (ushort_t*)carve(256 * 2);
  ushort_t* b2b  = (ushort_t*)carve(128 * 2);
  ushort_t* g2b  = (ushort_t*)carve(128 * 2);
  ushort_t* be2b = (ushort_t*)carve(128 * 2);
  int* offs = (int*)carve((size_t)(N + 1) * 4);
  int* srcS = (int*)carve((size_t)E * 4);
  int* csum = (int*)carve(256 * 4);
  int* cpre = (int*)carve(256 * 4);
  // zeroed region: deg(N) fill(N) sums(1024 floats)
  int nzero = 2 * N + 1024;
  int* zreg2 = (int*)carve((size_t)nzero * 4);
  int* deg   = zreg2;
  int* fill  = zreg2 + N;
  float* sum1 = (float*)(zreg2 + 2 * N);
  float* sq1  = sum1 + 256;
  float* sum2 = sum1 + 512;
  float* sq2  = sum1 + 640;
  int* eflag = (int*)carve(256);   // [0]=edge wide, [1]=float32 flag (setup writes)
  int* fF = eflag + 1;

  size_t needed = base - (uintptr_t)d_ws;
  if (needed > ws_size) return;

  // 1: zero + dtype detects
  setup_kernel<<<258, 256, 0, stream>>>(zreg2, N, (const int*)edges, 2 * E, eflag,
                                        (const unsigned int*)x0, N * 128, fF);
  // 2: x0 cvt + params + weight transposes + hist
  cvt_all_kernel<<<6145, 256, 0, stream>>>(x0, x0b, N * 128,
                                           b1, gw1, bw1, b2, gw2, bw2,
                                           b1b, g1b, be1b, b2b, g2b, be2b,
                                           Wq1, Wk1, Wv1, Wr1, wcat1,
                                           Wq2, Wk2, Wv2, Wr2, wcat2,
                                           edges, deg, E, N, eflag, fF);
  // 3-6: scan + scatter
  chunk_sum_kernel<<<NCHUNK, 256, 0, stream>>>(deg, csum, N);
  scan_small_kernel<<<1, 256, 0, stream>>>(csum, cpre, NCHUNK, offs, N);
  scan_final_kernel<<<NCHUNK, 256, 0, stream>>>(deg, cpre, offs, N);
  scatter_kernel<<<1024, 256, 0, stream>>>(edges, eflag, offs, fill, srcS, E, N);

  dim3 gA1(MT, 8);   // x = M tile, y = col tile (R11 best)
  dim3 gA2(MT, 6);
  int gAttn = (N + 3) / 4;        // one wave per node
  // Layer 1
  gemm4_kernel<<<gA1, 256, 0, stream>>>(x0b, wcat1, qb, kb, vb, hb, b1b,
                                        N, 128, 1024, 256, 512, 768);
  attn_kernel<<<gAttn, 256, 0, stream>>>(qb, kb, vb, offs, srcS, hb, 256, N);
  bn_stats_kernel<<<512, 256, 0, stream>>>(hb, sum1, sq1, N, 256);
  norm_relu_kernel<<<4096, 256, 0, stream>>>(hb, sum1, sq1, g1b, be1b, x1, N,
                                             (size_t)N * 256, 255);
  // Layer 2
  gemm4_kernel<<<gA2, 256, 0, stream>>>(x1, wcat2, qb, kb, vb, hb, b2b,
                                        N, 256, 768, 256, 512, 640);
  attn_kernel<<<gAttn, 256, 0, stream>>>(qb, kb, vb, offs, srcS, hb, 128, N);
  bn_stats_kernel<<<512, 128, 0, stream>>>(hb, sum2, sq2, N, 128);
  final_kernel<<<4096, 256, 0, stream>>>(hb, sum2, sq2, g2b, be2b, x0b, d_out, fF, N,
                                         (size_t)N * 128);
}